// Round 1
// 426.834 us; speedup vs baseline: 1.0008x; 1.0008x over previous
//
#include <hip/hip_runtime.h>
#include <stdint.h>

// Depth-to-space (r=4, x-major channel order), float32 in AND out.
// in:  (16, 4096, 32, 32) fp32   out: (16, 256, 128, 128) fp32
// out[b,c,y,x] = in[b, c*16 + 4*(x%4) + (y%4), y/4, x/4]
//
// Strategy: ALL global memory instructions are fully-contiguous 1-KiB wave
// accesses (float4/lane). The channel->pixel permute happens through a
// 16-KiB LDS tile:
//   load phase : each wave reads 1 KiB sequential runs of one input channel
//                (4 x dwordx4 loads at 16-KiB channel stride) and writes them
//                to LDS at consecutive addresses (conflict-free b128 writes).
//   store phase: each thread gathers its 4 output pixels (the 4 xr channels)
//                with stride-1024 ds_read_b32 (lanes span banks 0..31, only a
//                free 2-way alias), then stores float4 to a fully-sequential
//                16-KiB output span per block.
//
// Block = 256 threads handles (b, c, row-quarter q): 16 channels x 8 input
// rows (yb in [8q, 8q+8)) -> 32 contiguous output rows y in [32q, 32q+32).

__global__ __launch_bounds__(256) void ScaleTransfer_kernel(
    const float* __restrict__ in, float* __restrict__ out)
{
    __shared__ float lds[16 * 8 * 32];   // [ch 16][yb_local 8][col 32] = 16 KiB

    const int blk = blockIdx.x;
    const int q   = blk & 3;             // yb in [8q, 8q+8)
    const int bc  = blk >> 2;            // b*256 + c

    const int t    = threadIdx.x;
    const int wave = t >> 6;             // wave w stages channels 4*xr + w
    const int lane = t & 63;

    // ---- load phase: 4 fully-contiguous 1-KiB wave loads ----
    // element (ch = 4*xr + wave, yb = 8q + (lane>>3), col = 4*(lane&7)+s)
    // in-flat: bc*16384 + ch*1024 + (8q + lane>>3)*32 + 4*(lane&7)
    //        = bc*16384 + ch*1024 + q*256 + 4*lane
    const float* src = in + (size_t)bc * 16384 + (size_t)wave * 1024
                          + q * 256 + 4 * lane;
    float4 a0 = *(const float4*)(src + 0 * 4096);   // xr=0
    float4 a1 = *(const float4*)(src + 1 * 4096);   // xr=1
    float4 a2 = *(const float4*)(src + 2 * 4096);   // xr=2
    float4 a3 = *(const float4*)(src + 3 * 4096);   // xr=3

    // LDS at consecutive addresses per wave instruction: conflict-free b128
    float* l = lds + wave * 256 + 4 * lane;          // lds[ch][yb'][col]
    *(float4*)(l + 0 * 1024) = a0;
    *(float4*)(l + 1 * 1024) = a1;
    *(float4*)(l + 2 * 1024) = a2;
    *(float4*)(l + 3 * 1024) = a3;

    __syncthreads();

    // ---- store phase: LDS gather-transpose + contiguous global stores ----
    // out tile for this block = 32 rows x 128 floats, fully contiguous:
    // out + bc*16384 + q*4096 + 4*f,  f = t + 256*i
    float* dst = out + (size_t)bc * 16384 + (size_t)q * 4096 + 4 * t;
    #pragma unroll
    for (int i = 0; i < 4; ++i) {
        const int f  = t + 256 * i;
        const int yp = f >> 5;           // y' in [0,32): y = 32q + y'
        const int k  = f & 31;           // xb
        // out(y, 4k+xr) = in(ch = 4*xr + (y'&3), yb = 8q + (y'>>2), k)
        const float* g = lds + (yp & 3) * 256 + (yp >> 2) * 32 + k;
        float4 o;
        o.x = g[0 * 1024];               // xr=0
        o.y = g[1 * 1024];               // xr=1
        o.z = g[2 * 1024];               // xr=2
        o.w = g[3 * 1024];               // xr=3
        *(float4*)(dst + 1024 * i) = o;
    }
}

extern "C" void kernel_launch(void* const* d_in, const int* in_sizes, int n_in,
                              void* d_out, int out_size, void* d_ws, size_t ws_size,
                              hipStream_t stream) {
    const float* in = (const float*)d_in[0];
    float* out = (float*)d_out;
    // 16 batches * 256 out-channels * 4 row-quarters
    dim3 grid(16 * 256 * 4);
    dim3 block(256);
    ScaleTransfer_kernel<<<grid, block, 0, stream>>>(in, out);
}